// Round 1
// baseline (4053.213 us; speedup 1.0000x reference)
//
#include <hip/hip_runtime.h>

#define NROWS 262144
#define EPSV 1e-5f

// ws float offsets
#define WT4_OFF   0        // 4096 floats: lin4_wT[i][o]
#define SUMS_OFF  4096     // 262 floats: s1[131], s2[131]
#define SCALE_OFF 4608     // 131 floats
#define SHIFT_OFF 4864     // 131 floats

__global__ __launch_bounds__(256) void k_prep(const float* __restrict__ lin4_w,
                                              float* __restrict__ wT)
{
    int idx = blockIdx.x * 256 + threadIdx.x;   // 0..4095
    int o = idx & 63, i = idx >> 6;
    wT[i * 64 + o] = lin4_w[o * 64 + i];
}

__global__ __launch_bounds__(256) void k_stats(const float* __restrict__ sums,
                                               const float* __restrict__ bn_g,
                                               const float* __restrict__ bn_b,
                                               float* __restrict__ scale,
                                               float* __restrict__ shift)
{
    int j = threadIdx.x;
    if (j < 131) {
        const float inv = 1.0f / (float)NROWS;
        float mean = sums[j] * inv;
        float var  = sums[131 + j] * inv - mean * mean;
        var = fmaxf(var, 0.0f);
        float sc = bn_g[j] * rsqrtf(var + EPSV);
        scale[j] = sc;
        shift[j] = bn_b[j] - mean * sc;
    }
}

// Pass A: per-row MLP + RBF -> x(131) in regs -> h = x@W1^T + b1 -> d_out (row-major)
// plus per-column sum / sumsq accumulation for BN.
__global__ __launch_bounds__(256) void k_A(
    const float* __restrict__ corner, const float* __restrict__ normal,
    const float* __restrict__ conv_w, const float* __restrict__ conv_b,
    const float* __restrict__ lin3_w, const float* __restrict__ lin3_b,
    const float* __restrict__ lin4_wT, const float* __restrict__ lin4_b,
    const float* __restrict__ kern,
    const float* __restrict__ w1, const float* __restrict__ b1,
    float* __restrict__ h_out, float* __restrict__ sums)
{
    const int tid  = threadIdx.x;
    const int wave = tid >> 6, lane = tid & 63;
    const int row  = blockIdx.x * 256 + tid;
    const int row0 = blockIdx.x * 256 + wave * 64;

    // ---- inputs ----
    float cr[9];
    #pragma unroll
    for (int k = 0; k < 9; k++) cr[k] = corner[row * 9 + k];
    const float nr0 = normal[row * 3 + 0];
    const float nr1 = normal[row * 3 + 1];
    const float nr2 = normal[row * 3 + 2];

    // mean over the 3 pair-rows collapses (linearity): m = (c1+c2+c3)/3
    const float m0 = (cr[0] + cr[3] + cr[6]) * (1.0f / 3.0f);
    const float m1 = (cr[1] + cr[4] + cr[7]) * (1.0f / 3.0f);
    const float m2 = (cr[2] + cr[5] + cr[8]) * (1.0f / 3.0f);

    // ---- a[32] = m @ (conv_w[:, :3]+conv_w[:, 3:])^T + conv_b ----
    float a[32];
    #pragma unroll
    for (int o = 0; o < 32; o++) {
        const float* w = conv_w + o * 6;
        a[o] = conv_b[o] + m0 * (w[0] + w[3]) + m1 * (w[1] + w[4]) + m2 * (w[2] + w[5]);
    }

    // ---- v[64] = relu(a@lin3^T + b3) @ lin4^T + b4, streamed over hidden idx ----
    float v[64];
    #pragma unroll
    for (int o = 0; o < 64; o++) v[o] = lin4_b[o];
    for (int i3 = 0; i3 < 64; i3++) {
        float t = lin3_b[i3];
        const float* w = lin3_w + i3 * 32;
        #pragma unroll
        for (int i = 0; i < 32; i++) t += a[i] * w[i];
        t = fmaxf(t, 0.0f);
        const float* wt = lin4_wT + i3 * 64;
        #pragma unroll
        for (int o = 0; o < 64; o++) v[o] += t * wt[o];
    }

    // ---- z[64]: RBF over 64x4 kernel points ----
    float z[64];
    #pragma unroll
    for (int mi = 0; mi < 64; mi++) {
        float acc = 0.0f;
        #pragma unroll
        for (int l = 0; l < 4; l++) {
            const float* kp = kern + (mi * 4 + l) * 3;
            float d0 = nr0 - kp[0], d1 = nr1 - kp[1], d2 = nr2 - kp[2];
            acc += __expf(-(d0 * d0 + d1 * d1 + d2 * d2));
        }
        z[mi] = acc * 0.03125f;   // 0.5 / (K*4) = 1/32
    }

    // ---- conv1: h_j = b1[j] + x . W1[j,:], x = [normal(3), v(64), z(64)] ----
    __shared__ float lds[4][16][68];
    #pragma unroll
    for (int jb = 0; jb < 131; jb += 16) {
        const int jcnt = (jb + 16 <= 131) ? 16 : (131 - jb);
        for (int jj = 0; jj < jcnt; jj++) {
            const int j = jb + jj;
            const float* w = w1 + j * 131;
            float acc = b1[j];
            acc += nr0 * w[0] + nr1 * w[1] + nr2 * w[2];
            #pragma unroll
            for (int i = 0; i < 64; i++) acc += v[i] * w[3 + i];
            #pragma unroll
            for (int i = 0; i < 64; i++) acc += z[i] * w[67 + i];
            // BN stats: wave-reduce then one atomic per wave
            float s1 = acc, s2 = acc * acc;
            #pragma unroll
            for (int off = 32; off > 0; off >>= 1) {
                s1 += __shfl_xor(s1, off);
                s2 += __shfl_xor(s2, off);
            }
            if (lane == 0) {
                atomicAdd(&sums[j], s1);
                atomicAdd(&sums[131 + j], s2);
            }
            lds[wave][jj][lane] = acc;
        }
        __syncthreads();
        // coalesced flush: (r,c) -> h_out[(row0+r)*131 + jb + c]
        for (int k = 0; k < jcnt; k++) {
            int flat = k * 64 + lane;
            int r = flat / jcnt;          // constant jcnt after unroll
            int c = flat - r * jcnt;
            h_out[(row0 + r) * 131 + jb + c] = lds[wave][c][r];
        }
        __syncthreads();
    }
}

// Pass B: in-place on d_out: read h rows (staged/coalesced), BN+relu, conv2, write out.
__global__ __launch_bounds__(256) void k_B(
    const float* h_in, const float* __restrict__ scale,
    const float* __restrict__ shift,
    const float* __restrict__ w2, const float* __restrict__ b2,
    float* out)
{
    const int tid  = threadIdx.x;
    const int wave = tid >> 6, lane = tid & 63;
    const int row0 = blockIdx.x * 256 + wave * 64;
    __shared__ float lds[4][16][68];

    float hn[131];
    // ---- staged coalesced read of this wave's 64 rows + BN + relu ----
    #pragma unroll
    for (int jb = 0; jb < 131; jb += 16) {
        const int jcnt = (jb + 16 <= 131) ? 16 : (131 - jb);
        for (int k = 0; k < jcnt; k++) {
            int flat = k * 64 + lane;
            int r = flat / jcnt;
            int c = flat - r * jcnt;
            lds[wave][c][r] = h_in[(row0 + r) * 131 + jb + c];
        }
        __syncthreads();
        #pragma unroll
        for (int c = 0; c < 16; c++) {
            if (c < jcnt)
                hn[jb + c] = fmaxf(lds[wave][c][lane] * scale[jb + c] + shift[jb + c], 0.0f);
        }
        __syncthreads();
    }

    // ---- conv2 + staged coalesced write (in-place safe: all reads done above) ----
    #pragma unroll
    for (int ob = 0; ob < 131; ob += 16) {
        const int ocnt = (ob + 16 <= 131) ? 16 : (131 - ob);
        for (int oo = 0; oo < ocnt; oo++) {
            const int o = ob + oo;
            const float* w = w2 + o * 131;
            float acc = b2[o];
            #pragma unroll
            for (int i = 0; i < 131; i++) acc += hn[i] * w[i];
            lds[wave][oo][lane] = acc;
        }
        __syncthreads();
        for (int k = 0; k < ocnt; k++) {
            int flat = k * 64 + lane;
            int r = flat / ocnt;
            int c = flat - r * ocnt;
            out[(row0 + r) * 131 + ob + c] = lds[wave][c][r];
        }
        __syncthreads();
    }
}

extern "C" void kernel_launch(void* const* d_in, const int* in_sizes, int n_in,
                              void* d_out, int out_size, void* d_ws, size_t ws_size,
                              hipStream_t stream) {
    (void)in_sizes; (void)n_in; (void)out_size; (void)ws_size;
    const float* corner = (const float*)d_in[0];
    const float* normal = (const float*)d_in[1];
    // d_in[2] = neighbour (unused by reference)
    const float* conv_w = (const float*)d_in[3];
    const float* conv_b = (const float*)d_in[4];
    const float* lin3_w = (const float*)d_in[5];
    const float* lin3_b = (const float*)d_in[6];
    const float* lin4_w = (const float*)d_in[7];
    const float* lin4_b = (const float*)d_in[8];
    const float* kern   = (const float*)d_in[9];
    const float* w1     = (const float*)d_in[10];
    const float* b1     = (const float*)d_in[11];
    const float* bn_g   = (const float*)d_in[12];
    const float* bn_b   = (const float*)d_in[13];
    const float* w2     = (const float*)d_in[14];
    const float* b2     = (const float*)d_in[15];
    float* out = (float*)d_out;
    float* ws  = (float*)d_ws;

    hipMemsetAsync(ws + SUMS_OFF, 0, 262 * sizeof(float), stream);
    k_prep<<<16, 256, 0, stream>>>(lin4_w, ws + WT4_OFF);
    k_A<<<NROWS / 256, 256, 0, stream>>>(corner, normal, conv_w, conv_b,
                                         lin3_w, lin3_b, ws + WT4_OFF, lin4_b,
                                         kern, w1, b1, out, ws + SUMS_OFF);
    k_stats<<<1, 256, 0, stream>>>(ws + SUMS_OFF, bn_g, bn_b,
                                   ws + SCALE_OFF, ws + SHIFT_OFF);
    k_B<<<NROWS / 256, 256, 0, stream>>>(out, ws + SCALE_OFF, ws + SHIFT_OFF,
                                         w2, b2, out);
}